// Round 7
// baseline (539.352 us; speedup 1.0000x reference)
//
#include <hip/hip_runtime.h>
#include <math.h>

#define B 256
#define F 512
#define C 100000
#define S_SCALE 64.0f
#define M_MARGIN 0.4f
#define K_VP 0.7f

#define BN 32
#define NTILES (C / BN)          // 3125 exact (C % 32 == 0): no tail guards
#define NT_TOT (2 * NTILES)      // 6250 flat tiles (src0: weight, src1: queue)
#define NPAIRS NTILES            // 3125 tile-pairs; pair pr = flat tiles (2pr, 2pr+1)
#define NBLK 512                 // persistent blocks

typedef __bf16 bf16x8 __attribute__((ext_vector_type(8)));
typedef float  floatx4 __attribute__((ext_vector_type(4)));

// ---------- fused: emb = l2norm(input) -> swizzled bf16 A + newrows (exact fp32) ----------
// embb_sw layout: A-frag for (rowtile R, kstep ks) at 1KB region ((R*16+ks)*64 + lane)*16B,
// lane = (row&15) + 16*q, element j: k = ks*32 + q*8 + j.
__global__ void embnew_kernel(const float* __restrict__ input, const float* __restrict__ queue,
                              const int* __restrict__ label,
                              __bf16* __restrict__ embb_sw, float* __restrict__ newrows) {
    int i = blockIdx.x;
    int t = threadIdx.x;
    const float* x = input + (size_t)i * F;
    float x0 = x[t], x1 = x[t + 256];
    float p = x0 * x0 + x1 * x1;
    __shared__ float red[4];
    for (int off = 32; off > 0; off >>= 1) p += __shfl_down(p, off, 64);
    if ((t & 63) == 0) red[t >> 6] = p;
    __syncthreads();
    float tot = red[0] + red[1] + red[2] + red[3];
    float inv = 1.0f / fmaxf(sqrtf(tot), 1e-5f);
    float e0 = x0 * inv, e1 = x1 * inv;
    {
        int R = i >> 4, ln = i & 15;
        int k = t;
        embb_sw[(size_t)(((R * 16 + (k >> 5)) * 64 + ln + 16 * ((k & 31) >> 3)) * 8 + (k & 7))] = (__bf16)e0;
        k = t + 256;
        embb_sw[(size_t)(((R * 16 + (k >> 5)) * 64 + ln + 16 * ((k & 31) >> 3)) * 8 + (k & 7))] = (__bf16)e1;
    }
    int l = label[i];
    const float* qr = queue + (size_t)l * F;
    float q0 = qr[t], q1 = qr[t + 256];
    float pd = q0 * e0 + q1 * e1;
    __syncthreads();
    for (int off = 32; off > 0; off >>= 1) pd += __shfl_down(pd, off, 64);
    if ((t & 63) == 0) red[t >> 6] = pd;
    __syncthreads();
    float drift = red[0] + red[1] + red[2] + red[3];
    float f = drift / (1.0f + fabsf(drift));   // softsign
    float v0 = f * q0 + (1.0f - f) * e0;
    float v1 = f * q1 + (1.0f - f) * e1;
    float p2 = v0 * v0 + v1 * v1;
    __syncthreads();
    for (int off = 32; off > 0; off >>= 1) p2 += __shfl_down(p2, off, 64);
    if ((t & 63) == 0) red[t >> 6] = p2;
    __syncthreads();
    float tot2 = red[0] + red[1] + red[2] + red[3];
    float inv2 = 1.0f / fmaxf(sqrtf(tot2), 1e-12f);
    newrows[(size_t)i * F + t]       = v0 * inv2;
    newrows[(size_t)i * F + t + 256] = v1 * inv2;
}

// ---------- map[c] = -1 ----------
__global__ void init_kernel(int* __restrict__ map) {
    int idx = blockIdx.x * 256 + threadIdx.x;
    if (idx < C) map[idx] = -1;
}

// ---------- last-occurrence-wins scatter (numpy queue[label]=rows semantics) ----------
__global__ void scatter_kernel(const int* __restrict__ label, int* __restrict__ map) {
    atomicMax(&map[label[threadIdx.x]], (int)threadIdx.x);
}

// ---------- persistent pipelined bf16 MFMA GEMM + EPL epilogue, TILE-PAIR version ------
// Round-6 diagnosis: the invisible cost is A-fragment L2 traffic -- 256KB/tile/CU of
// embb_sw re-reads (doesn't fit 32KB L1, invisible in FETCH_SIZE) against 64KB of B.
// Fix: consecutive tiles share the SAME A rows, so process a PAIR of tiles per pass:
// stage both B-tiles (2 x 32KB LDS), one MFMA loop reads each `a` ONCE and feeds 4 MFMAs
// (2 tiles x 2 col-groups). A-traffic per B-byte halves; per-tile barrier count halves;
// prefetch depth doubles (8 dwordx4 in flight under the MFMA window).
// Launch bounds stay (1024,4): VGPR target ~110 < 128 (4 waves/SIMD). Round 5 proved
// pledging 8 waves spills; round 6 proved VGPR=64 still yields only 1 block/CU -- so
// TLP is unreachable and the lever must be per-CU traffic (this change).
// LDS B layout per buffer: 32 x 1KB regions; region (ks*2+ct), slot lane = (c&15)+16*q,
// elems k = ks*32+q*8+j. Staging wave w: ct=w&1, ks in {w>>1,(w>>1)+8}; each thread owns
// ONE column per tile (register sumsq); all ds ops lane-linear (conflict-free).
__global__ __launch_bounds__(1024, 4) void gemm_epl_kernel(
        const __bf16* __restrict__ embb_sw,
        const float* __restrict__ weight,
        const float* __restrict__ queue,
        const float* __restrict__ newrows,
        const int* __restrict__ map,
        const int* __restrict__ label,
        float* __restrict__ partials,
        float* __restrict__ posvals) {
    int tid = threadIdx.x;
    int w = tid >> 6;          // 0..15
    int l = tid & 63;
    int ln = l & 15;
    int q = l >> 4;
    int ctS = w & 1;           // staging col-group
    int ksA = w >> 1;          // staging ks pair {ksA, ksA+8}
    int cl = ctS * 16 + ln;    // the one column (per tile) this thread stages

    __shared__ __align__(16) __bf16 bS[2][32 * 512];   // 2 x 32KB frag-region buffers (pair)
    __shared__ float colpart_s[2][32][33];             // per pair-element, padded
    __shared__ float colinv_s[2][32];
    __shared__ int label_s[B];

    if (tid < B) label_s[tid] = label[tid];

    int p0 = (int)(((long)blockIdx.x * NPAIRS) / NBLK);
    int p1 = (int)(((long)(blockIdx.x + 1) * NPAIRS) / NBLK);

    float4 u[8];                                 // next pair's staged fp32 (in flight)
    float ns0[4] = {0.f, 0.f, 0.f, 0.f};         // per-row negative-exp accum, src0
    float ns1[4] = {0.f, 0.f, 0.f, 0.f};         // src1 (static arrays: rule-#20 safe)

    auto tptr = [&](int ft) -> const float* {
        int s1 = (ft >= NTILES);
        int tile = ft - s1 * NTILES;
        int c = tile * BN + cl;
        if (!s1) return weight + (size_t)c * F;
        int mi = map[c];
        return (mi >= 0) ? newrows + (size_t)mi * F : queue + (size_t)c * F;
    };
    auto issue_loads = [&](int pr) {             // 8 dwordx4, stay in flight
        int k0 = ksA * 32 + q * 8;
        const float* bp0 = tptr(2 * pr);
        const float* bp1 = tptr(2 * pr + 1);
        u[0] = *(const float4*)(bp0 + k0);
        u[1] = *(const float4*)(bp0 + k0 + 4);
        u[2] = *(const float4*)(bp0 + k0 + 256);   // (ksA+8)*32 + q*8
        u[3] = *(const float4*)(bp0 + k0 + 260);
        u[4] = *(const float4*)(bp1 + k0);
        u[5] = *(const float4*)(bp1 + k0 + 4);
        u[6] = *(const float4*)(bp1 + k0 + 256);
        u[7] = *(const float4*)(bp1 + k0 + 260);
    };

    issue_loads(p0);   // first pair not overlapped

    for (int pr = p0; pr < p1; ++pr) {
        int s1a = (2 * pr     >= NTILES);
        int s1b = (2 * pr + 1 >= NTILES);
        int cba = (2 * pr     - s1a * NTILES) * BN;
        int cbb = (2 * pr + 1 - s1b * NTILES) * BN;

        // ---- convert + lane-linear ds_write, both halves (vmcnt drains here,
        //      under previous pair's MFMA+epilogue cover). H is a literal -> static idx.
#define CVT_HALF(H)                                                                     \
        {                                                                               \
            float4 u0 = u[4*H], u1 = u[4*H+1], u2 = u[4*H+2], u3 = u[4*H+3];            \
            float ss = u0.x*u0.x + u0.y*u0.y + u0.z*u0.z + u0.w*u0.w                    \
                     + u1.x*u1.x + u1.y*u1.y + u1.z*u1.z + u1.w*u1.w                    \
                     + u2.x*u2.x + u2.y*u2.y + u2.z*u2.z + u2.w*u2.w                    \
                     + u3.x*u3.x + u3.y*u3.y + u3.z*u3.z + u3.w*u3.w;                   \
            bf16x8 pa, pb;                                                              \
            pa[0]=(__bf16)u0.x; pa[1]=(__bf16)u0.y; pa[2]=(__bf16)u0.z; pa[3]=(__bf16)u0.w; \
            pa[4]=(__bf16)u1.x; pa[5]=(__bf16)u1.y; pa[6]=(__bf16)u1.z; pa[7]=(__bf16)u1.w; \
            pb[0]=(__bf16)u2.x; pb[1]=(__bf16)u2.y; pb[2]=(__bf16)u2.z; pb[3]=(__bf16)u2.w; \
            pb[4]=(__bf16)u3.x; pb[5]=(__bf16)u3.y; pb[6]=(__bf16)u3.z; pb[7]=(__bf16)u3.w; \
            *(bf16x8*)&bS[H][(((ksA * 2 + ctS) * 64 + l) * 8)]       = pa;              \
            *(bf16x8*)&bS[H][((((ksA + 8) * 2 + ctS) * 64 + l) * 8)] = pb;              \
            colpart_s[H][cl][ksA * 4 + q] = ss;                                         \
        }
        CVT_HALF(0)
        CVT_HALF(1)
#undef CVT_HALF
        __syncthreads();   // (A): both bS buffers + colpart ready

        if (tid < 64) {
            int e = tid >> 5, cc = tid & 31;
            float s = 0.f;
#pragma unroll
            for (int p = 0; p < 32; ++p) s += colpart_s[e][cc][p];
            int s1e = e ? s1b : s1a;
            colinv_s[e][cc] = 1.0f / fmaxf(sqrtf(s), s1e ? 1e-12f : 1e-5f);
        }

        if (pr + 1 < p1) issue_loads(pr + 1);   // 8 loads fly under the MFMA window

        // ---- MFMA: each `a` read ONCE from L2, feeds 4 MFMAs (2 tiles x 2 col-groups)
        floatx4 acc00 = (floatx4){0.f,0.f,0.f,0.f}, acc01 = (floatx4){0.f,0.f,0.f,0.f};
        floatx4 acc10 = (floatx4){0.f,0.f,0.f,0.f}, acc11 = (floatx4){0.f,0.f,0.f,0.f};
#pragma unroll
        for (int ks = 0; ks < 16; ++ks) {
            bf16x8 a = *(const bf16x8*)(embb_sw + ((size_t)((w * 16 + ks) * 64 + l) << 3));
            bf16x8 b00 = *(const bf16x8*)&bS[0][(((ks * 2 + 0) * 64 + l) * 8)];
            bf16x8 b01 = *(const bf16x8*)&bS[0][(((ks * 2 + 1) * 64 + l) * 8)];
            bf16x8 b10 = *(const bf16x8*)&bS[1][(((ks * 2 + 0) * 64 + l) * 8)];
            bf16x8 b11 = *(const bf16x8*)&bS[1][(((ks * 2 + 1) * 64 + l) * 8)];
            acc00 = __builtin_amdgcn_mfma_f32_16x16x32_bf16(a, b00, acc00, 0, 0, 0);
            acc01 = __builtin_amdgcn_mfma_f32_16x16x32_bf16(a, b01, acc01, 0, 0, 0);
            acc10 = __builtin_amdgcn_mfma_f32_16x16x32_bf16(a, b10, acc10, 0, 0, 0);
            acc11 = __builtin_amdgcn_mfma_f32_16x16x32_bf16(a, b11, acc11, 0, 0, 0);
        }
        __syncthreads();   // (B): colinv visible; bS reads done (next writes after this)

        // ---- epilogue, both pair elements; SRC/E literals, uniform branch on s1
#define EPL_TILE(A0, A1, CB, E, SRC, NS)                                      \
        _Pragma("unroll")                                                     \
        for (int r = 0; r < 4; ++r) {                                         \
            int row = w * 16 + q * 4 + r;                                     \
            int lab = label_s[row];                                           \
            float v0 = A0[r] * colinv_s[E][ln];                               \
            float v1 = A1[r] * colinv_s[E][16 + ln];                          \
            if (CB + ln == lab) posvals[SRC * B + row] = v0;                  \
            else NS[r] += __expf(S_SCALE * v0);                               \
            if (CB + 16 + ln == lab) posvals[SRC * B + row] = v1;             \
            else NS[r] += __expf(S_SCALE * v1);                               \
        }
        if (!s1a) { EPL_TILE(acc00, acc01, cba, 0, 0, ns0) }
        else      { EPL_TILE(acc00, acc01, cba, 0, 1, ns1) }
        if (!s1b) { EPL_TILE(acc10, acc11, cbb, 1, 0, ns0) }
        else      { EPL_TILE(acc10, acc11, cbb, 1, 1, ns1) }
#undef EPL_TILE
    }

    // ---- block-end: reduce ns over the 16-lane col group, one packed store per row
#pragma unroll
    for (int r = 0; r < 4; ++r) {
#pragma unroll
        for (int off = 1; off <= 8; off <<= 1) {
            ns0[r] += __shfl_xor(ns0[r], off, 64);
            ns1[r] += __shfl_xor(ns1[r], off, 64);
        }
    }
    if (ln == 0) {
        int rb = w * 16 + q * 4;
        float4 a = make_float4(ns0[0], ns0[1], ns0[2], ns0[3]);
        float4 b = make_float4(ns1[0], ns1[1], ns1[2], ns1[3]);
        *(float4*)&partials[(size_t)blockIdx.x * 512 + rb]       = a;   // src0 rows
        *(float4*)&partials[(size_t)blockIdx.x * 512 + 256 + rb] = b;   // src1 rows
    }
}

// ---------- fused reduce + EPL loss: negacc[j] = sum_bx partials; then loss ----------
__global__ void finish_kernel(const float* __restrict__ partials,
                              const float* __restrict__ posvals,
                              float* __restrict__ out) {
    int j = threadIdx.x;   // 0..511
    float s = 0.f;
    for (int bx = 0; bx < NBLK; ++bx) s += partials[(size_t)bx * 512 + j];  // coalesced in j
    __shared__ float neg[512];
    neg[j] = s;
    __syncthreads();
    float p = 0.f;
    if (j < 256) {
        float l1 = log1pf(neg[j]       * __expf(-S_SCALE * (posvals[j] - M_MARGIN)));
        float l2 = log1pf(neg[256 + j] * __expf(-S_SCALE * (1.0f - K_VP) * posvals[256 + j]));
        p = l1 + l2;
    }
    for (int off = 32; off > 0; off >>= 1) p += __shfl_down(p, off, 64);
    __shared__ float red[8];
    if ((j & 63) == 0) red[j >> 6] = p;
    __syncthreads();
    if (j == 0) {
        float t = 0.f;
#pragma unroll
        for (int i = 0; i < 8; ++i) t += red[i];
        out[0] = t / (2.0f * B);
    }
}

extern "C" void kernel_launch(void* const* d_in, const int* in_sizes, int n_in,
                              void* d_out, int out_size, void* d_ws, size_t ws_size,
                              hipStream_t stream) {
    const float* input  = (const float*)d_in[0];
    const float* weight = (const float*)d_in[1];
    const float* queue  = (const float*)d_in[2];
    const int*   label  = (const int*)d_in[3];
    float* out = (float*)d_out;

    char* ws = (char*)d_ws;
    __bf16* embb_sw  = (__bf16*)(ws);                         // 256 KB
    float*  newrows  = (float*)(ws + (256 << 10));            // 512 KB
    float*  posvals  = (float*)(ws + (768 << 10) + 2048);     // 2 KB
    int*    map      = (int*)  (ws + (768 << 10) + 4096);     // 400 KB
    float*  partials = (float*)(ws + (1200 << 10));           // 512*512*4 = 1 MB

    init_kernel<<<(C + 255) / 256, 256, 0, stream>>>(map);
    scatter_kernel<<<1, B, 0, stream>>>(label, map);
    embnew_kernel<<<B, 256, 0, stream>>>(input, queue, label, embb_sw, newrows);
    gemm_epl_kernel<<<NBLK, 1024, 0, stream>>>(embb_sw, weight, queue, newrows, map,
                                               label, partials, posvals);
    finish_kernel<<<1, 512, 0, stream>>>(partials, posvals, out);
}